// Round 1
// baseline (2137.480 us; speedup 1.0000x reference)
//
#include <hip/hip_runtime.h>
#include <math.h>

#define N_NODES 20000
#define E_EDGES 160000
#define LAT 128
#define MUL 16
#define DD 9
#define TPD 48

// ---- workspace layout (float offsets) ----
#define WS_Q      ((size_t)0)
#define WS_K      (WS_Q + (size_t)N_NODES*LAT)
#define WS_V      (WS_K + (size_t)N_NODES*LAT)
#define WS_S      (WS_V + (size_t)N_NODES*LAT)
#define WS_W48    (WS_S + (size_t)N_NODES*LAT)
#define WS_SPAT   (WS_W48 + (size_t)E_EDGES*TPD)
#define WS_ALPHA  (WS_SPAT + (size_t)E_EDGES*LAT)     // alpha, then overwritten with ex
#define WS_ZERO   (WS_ALPHA + (size_t)E_EDGES*4)      // start of zeroed region
#define WS_AMAX   WS_ZERO                              // uint-mapped max, N*4
#define WS_DEN    (WS_AMAX + (size_t)N_NODES*4)
#define WS_HSUM   (WS_DEN + (size_t)N_NODES*4)
#define WS_NDX    (WS_HSUM + (size_t)N_NODES*LAT)
#define WS_END    (WS_NDX + (size_t)N_NODES*MUL*DD)
#define ZERO_CNT  (WS_END - WS_ZERO)

#define DEVI __device__ __forceinline__

DEVI float silu_f(float x){ return x / (1.f + expf(-x)); }
DEVI unsigned int fmap(float x){ unsigned int b=__float_as_uint(x); return (b&0x80000000u)? ~b : (b|0x80000000u); }
DEVI float funmap(unsigned int u){ return (u&0x80000000u)? __uint_as_float(u&0x7fffffffu) : __uint_as_float(~u); }

// acc[r] += sum_k src[r*LDSTRIDE+k] * W[k*wstride + t], src in LDS (broadcast reads)
template<int R, int KD, int LDSTRIDE>
DEVI void mm_acc(const float* src, const float* __restrict__ W, int wstride, int t, float* acc){
  #pragma unroll 2
  for (int k=0;k<KD;k+=4){
    float4 xv[R];
    #pragma unroll
    for (int r=0;r<R;++r) xv[r] = *(const float4*)(src + r*LDSTRIDE + k);
    #pragma unroll
    for (int kk=0;kk<4;++kk){
      float wk = W[(size_t)(k+kk)*wstride + t];
      #pragma unroll
      for (int r=0;r<R;++r) acc[r] += ((const float*)&xv[r])[kk]*wk;
    }
  }
}

// ---- K0: zero the accumulator region ----
__global__ void k0_zero(float* __restrict__ z){
  size_t i = (size_t)blockIdx.x*256 + threadIdx.x;
  if (i < ZERO_CNT) z[i] = 0.f;
}

// ---- K1: per-node Q,K,V(gv mlp),S(gs mlp) ----
__global__ __launch_bounds__(128) void k1_node(const float* __restrict__ h,
  const float* __restrict__ Wq_W,const float* __restrict__ Wq_b,
  const float* __restrict__ Wk_W,const float* __restrict__ Wk_b,
  const float* __restrict__ gv_W1,const float* __restrict__ gv_b1,
  const float* __restrict__ gv_W2,const float* __restrict__ gv_b2,
  const float* __restrict__ gs_W1,const float* __restrict__ gs_b1,
  const float* __restrict__ gs_W2,const float* __restrict__ gs_b2,
  float* __restrict__ ws)
{
  __shared__ float hx[16][LAT], hid[16][LAT];
  const int t=threadIdx.x, n0=blockIdx.x*16;
  for (int idx=t; idx<2048; idx+=128){ int r=idx>>7,c=idx&127; hx[r][c]=h[(size_t)(n0+r)*LAT+c]; }
  __syncthreads();
  float acc[16];
  float* Qp=ws+WS_Q; float* Kp=ws+WS_K; float* Vp=ws+WS_V; float* Sp=ws+WS_S;
  { float b=Wq_b[t]; for(int r=0;r<16;++r)acc[r]=b; mm_acc<16,LAT,LAT>(&hx[0][0],Wq_W,LAT,t,acc);
    for(int r=0;r<16;++r) Qp[(size_t)(n0+r)*LAT+t]=acc[r]; }
  { float b=Wk_b[t]; for(int r=0;r<16;++r)acc[r]=b; mm_acc<16,LAT,LAT>(&hx[0][0],Wk_W,LAT,t,acc);
    for(int r=0;r<16;++r) Kp[(size_t)(n0+r)*LAT+t]=acc[r]; }
  { float b=gv_b1[t]; for(int r=0;r<16;++r)acc[r]=b; mm_acc<16,LAT,LAT>(&hx[0][0],gv_W1,LAT,t,acc);
    for(int r=0;r<16;++r) hid[r][t]=silu_f(acc[r]); }
  __syncthreads();
  { float b=gv_b2[t]; for(int r=0;r<16;++r)acc[r]=b; mm_acc<16,LAT,LAT>(&hid[0][0],gv_W2,LAT,t,acc);
    for(int r=0;r<16;++r) Vp[(size_t)(n0+r)*LAT+t]=acc[r]; }
  __syncthreads();
  { float b=gs_b1[t]; for(int r=0;r<16;++r)acc[r]=b; mm_acc<16,LAT,LAT>(&hx[0][0],gs_W1,LAT,t,acc);
    for(int r=0;r<16;++r) hid[r][t]=silu_f(acc[r]); }
  __syncthreads();
  { float b=gs_b2[t]; for(int r=0;r<16;++r)acc[r]=b; mm_acc<16,LAT,LAT>(&hid[0][0],gs_W2,LAT,t,acc);
    for(int r=0;r<16;++r) Sp[(size_t)(n0+r)*LAT+t]=acc[r]; }
}

// ---- K2: per-edge w (eq_linear + vector rejection + per-slice dots) ----
__global__ __launch_bounds__(256) void k2_edge_w(
  const float* __restrict__ Xin, const float* __restrict__ sph,
  const float* __restrict__ Wtq, const float* __restrict__ Wtk,
  const int* __restrict__ ec, const int* __restrict__ en, float* __restrict__ ws)
{
  __shared__ float xc[16][144], xn[16][144], sphL[16][9];
  __shared__ float wq[768], wkk[768];
  __shared__ int ceI[16], nbI[16];
  const int tid=threadIdx.x, e0=blockIdx.x*16;
  if (tid<16){ ceI[tid]=ec[e0+tid]; nbI[tid]=en[e0+tid]; }
  for (int idx=tid; idx<768; idx+=256){ wq[idx]=Wtq[idx]; wkk[idx]=Wtk[idx]; }
  __syncthreads();
  for (int idx=tid; idx<2304; idx+=256){ int r=idx/144,c=idx%144;
    xc[r][c]=Xin[(size_t)ceI[r]*144+c]; xn[r][c]=Xin[(size_t)nbI[r]*144+c]; }
  if (tid<144){ int r=tid/9,c=tid%9; sphL[r][c]=sph[(size_t)(e0+r)*9+c]; }
  __syncthreads();
  const int el=tid>>4, j=tid&15;
  float xq[9], xk[9];
  const int ss[3]={0,1,4}, se[3]={1,4,9};
  #pragma unroll
  for (int l=0;l<3;++l){
    for (int m=ss[l]; m<se[l]; ++m){
      float aq=0.f, ak=0.f;
      #pragma unroll
      for (int i=0;i<16;++i){
        float wql = wq[l*256 + j*16 + i], wkl = wkk[l*256 + j*16 + i];
        aq += wql*xc[el][i*9+m];
        ak += wkl*xn[el][i*9+m];
      }
      xq[m]=aq; xk[m]=ak;
    }
  }
  float dq=0.f, dk=0.f;
  #pragma unroll
  for (int d=0; d<9; ++d){ dq += xq[d]*sphL[el][d]; dk += xk[d]*sphL[el][d]; }
  #pragma unroll
  for (int d=0; d<9; ++d){ xq[d] -= dq*sphL[el][d]; xk[d] -= dk*sphL[el][d]; }
  const float isc[3] = {1.f, 0.5773502691896258f, 0.4472135954999579f};
  #pragma unroll
  for (int l=0;l<3;++l){
    float s=0.f;
    for (int m=ss[l]; m<se[l]; ++m) s += xq[m]*xk[m];
    ws[WS_W48 + (size_t)(e0+el)*TPD + l*16 + j] = s*isc[l];
  }
}

// ---- K3: per-edge t-update + spatial + alpha (+ segment max) ----
__global__ __launch_bounds__(256) void k3_edge_t(
  const float* __restrict__ t_in, const int* __restrict__ ec, const int* __restrict__ en,
  const float* __restrict__ gw_W1,const float* __restrict__ gw_b1,
  const float* __restrict__ gw_W2,const float* __restrict__ gw_b2,
  const float* __restrict__ gt_W1,const float* __restrict__ gt_b1,
  const float* __restrict__ gt_W2,const float* __restrict__ gt_b2,
  const float* __restrict__ Wrs_W,const float* __restrict__ Wrs_b,
  const float* __restrict__ Wre_W,
  const float* __restrict__ ucp, float* __restrict__ ws, float* __restrict__ outT)
{
  __shared__ float tin[16][LAT], wb[16][TPD], hid[16][LAT], tnw[16][LAT], qc[16][LAT], kn[16][LAT];
  __shared__ int ceI[16], nbI[16];
  const int tid=threadIdx.x, t=tid&127, g=tid>>7, rb=g*8;
  const int e0=blockIdx.x*16;
  if (tid<16){ ceI[tid]=ec[e0+tid]; nbI[tid]=en[e0+tid]; }
  __syncthreads();
  const float* Qp = ws+WS_Q; const float* Kp = ws+WS_K; const float* Sp = ws+WS_S;
  for (int idx=tid; idx<2048; idx+=256){ int r=idx>>7,c=idx&127;
    tin[r][c]=t_in[(size_t)(e0+r)*LAT+c];
    qc[r][c]=Qp[(size_t)ceI[r]*LAT+c];
    kn[r][c]=Kp[(size_t)nbI[r]*LAT+c]; }
  for (int idx=tid; idx<16*TPD; idx+=256){ int r=idx/TPD,c=idx%TPD; wb[r][c]=ws[WS_W48+(size_t)(e0+r)*TPD+c]; }
  __syncthreads();
  const float uc=ucp[0], co=rsqrtf(uc*uc+1.f), ucco=uc*co;
  float acc[8], accw[8], acct[8];
  // gw hidden
  { float b=gw_b1[t];
    #pragma unroll
    for(int r=0;r<8;++r) acc[r]=b;
    mm_acc<8,TPD,TPD>(&wb[rb][0], gw_W1, LAT, t, acc);
    #pragma unroll
    for(int r=0;r<8;++r) hid[rb+r][t]=silu_f(acc[r]); }
  __syncthreads();
  // gw out
  { float b=gw_b2[t];
    #pragma unroll
    for(int r=0;r<8;++r) accw[r]=b;
    mm_acc<8,LAT,LAT>(&hid[rb][0], gw_W2, LAT, t, accw); }
  __syncthreads();
  // gt hidden
  { float b=gt_b1[t];
    #pragma unroll
    for(int r=0;r<8;++r) acc[r]=b;
    mm_acc<8,LAT,LAT>(&tin[rb][0], gt_W1, LAT, t, acc);
    #pragma unroll
    for(int r=0;r<8;++r) hid[rb+r][t]=silu_f(acc[r]); }
  __syncthreads();
  // gt out
  { float b=gt_b2[t];
    #pragma unroll
    for(int r=0;r<8;++r) acct[r]=b;
    mm_acc<8,LAT,LAT>(&hid[rb][0], gt_W2, LAT, t, acct); }
  // residual -> t_new
  #pragma unroll
  for(int r=0;r<8;++r){
    float tn = co*tin[rb+r][t] + ucco*accw[r]*acct[r];
    tnw[rb+r][t]=tn;
    outT[(size_t)(e0+rb+r)*LAT+t]=tn;
  }
  __syncthreads();
  // spatial = (t_new@Wrs + b) * S[nb]
  { float b=Wrs_b[t];
    #pragma unroll
    for(int r=0;r<8;++r) acc[r]=b;
    mm_acc<8,LAT,LAT>(&tnw[rb][0], Wrs_W, LAT, t, acc);
    #pragma unroll
    for(int r=0;r<8;++r){
      ws[WS_SPAT+(size_t)(e0+rb+r)*LAT+t] = acc[r]*Sp[(size_t)nbI[rb+r]*LAT+t];
    } }
  // ta = silu(t_new@Wre); alpha
  { 
    #pragma unroll
    for(int r=0;r<8;++r) acc[r]=0.f;
    mm_acc<8,LAT,LAT>(&tnw[rb][0], Wre_W, LAT, t, acc);
    unsigned int* amaxu = (unsigned int*)(ws + WS_AMAX);
    #pragma unroll
    for(int r=0;r<8;++r){
      float p = qc[rb+r][t]*kn[rb+r][t]*silu_f(acc[r]);
      for (int off=16; off; off>>=1) p += __shfl_down(p, off, 32);
      if ((t&31)==0){
        float aval = p * 0.17677669529663687f;  // 1/sqrt(32)
        int e = e0+rb+r, hh = t>>5;
        ws[WS_ALPHA + (size_t)e*4 + hh] = aval;
        atomicMax(&amaxu[(size_t)ceI[rb+r]*4 + hh], fmap(aval));
      }
    }
  }
}

// ---- K4: ex = exp(alpha - amax[center]); den += ex ----
__global__ __launch_bounds__(256) void k4_softmax(const int* __restrict__ ec, float* __restrict__ ws){
  int i = blockIdx.x*256 + threadIdx.x;
  if (i >= E_EDGES*4) return;
  int e = i>>2, hh = i&3;
  int c = ec[e];
  float a = ws[WS_ALPHA + i];
  const unsigned int* amaxu = (const unsigned int*)(ws + WS_AMAX);
  float am = funmap(amaxu[(size_t)c*4+hh]);
  float exv = expf(a - am);
  ws[WS_ALPHA + i] = exv;
  atomicAdd(&ws[WS_DEN + (size_t)c*4 + hh], exv);
}

// ---- K5: per-edge gates, segment sums for dh and dX ----
__global__ __launch_bounds__(256) void k5_edge_gate(
  const float* __restrict__ Xin, const float* __restrict__ sph,
  const int* __restrict__ ec, const int* __restrict__ en,
  const float* __restrict__ gsp_W1,const float* __restrict__ gsp_b1,
  const float* __restrict__ gsp_W2,const float* __restrict__ gsp_b2,
  const float* __restrict__ md_W1,const float* __restrict__ md_b1,
  const float* __restrict__ md_W2,const float* __restrict__ md_b2,
  const float* __restrict__ mt_W1,const float* __restrict__ mt_b1,
  const float* __restrict__ mt_W2,const float* __restrict__ mt_b2,
  float* __restrict__ ws)
{
  __shared__ float comb[16][LAT], hidA[16][LAT], od[16][LAT], ot[16][LAT], hidB[16][LAT];
  __shared__ float xnb[16][144], sphL[16][9], attnL[16][4], gdL[16][16], gtL[16][16];
  __shared__ int ceI[16], nbI[16];
  const int tid=threadIdx.x, t=tid&127, g=tid>>7, rb=g*8;
  const int e0=blockIdx.x*16;
  if (tid<16){ ceI[tid]=ec[e0+tid]; nbI[tid]=en[e0+tid]; }
  __syncthreads();
  const float* Vp = ws+WS_V; const float* spat = ws+WS_SPAT;
  const float* exb = ws+WS_ALPHA; const float* den = ws+WS_DEN;
  if (tid<64){ int r=tid>>2, hh=tid&3;
    attnL[r][hh] = exb[(size_t)(e0+r)*4+hh] / den[(size_t)ceI[r]*4+hh]; }
  if (tid<144){ int r=tid/9,c=tid%9; sphL[r][c]=sph[(size_t)(e0+r)*9+c]; }
  for (int idx=tid; idx<2304; idx+=256){ int r=idx/144,c=idx%144; xnb[r][c]=Xin[(size_t)nbI[r]*144+c]; }
  __syncthreads();
  for (int idx=tid; idx<2048; idx+=256){ int r=idx>>7,c=idx&127;
    comb[r][c] = attnL[r][c>>5]*Vp[(size_t)nbI[r]*LAT+c] + spat[(size_t)(e0+r)*LAT+c]; }
  __syncthreads();
  float acc[8];
  // gsp hidden
  { float b=gsp_b1[t];
    #pragma unroll
    for(int r=0;r<8;++r)acc[r]=b;
    mm_acc<8,LAT,LAT>(&comb[rb][0], gsp_W1, LAT, t, acc);
    #pragma unroll
    for(int r=0;r<8;++r) hidA[rb+r][t]=silu_f(acc[r]); }
  __syncthreads();
  // gsp out: o_s (atomic to hsum), o_d, o_t
  { float accS[8],accD[8],accT[8];
    float bS=gsp_b2[t], bD=gsp_b2[128+t], bT=gsp_b2[256+t];
    #pragma unroll
    for(int r=0;r<8;++r){accS[r]=bS;accD[r]=bD;accT[r]=bT;}
    #pragma unroll 2
    for (int k=0;k<LAT;k+=4){
      float4 xv[8];
      #pragma unroll
      for(int r=0;r<8;++r) xv[r]=*(const float4*)&hidA[rb+r][k];
      #pragma unroll
      for(int kk=0;kk<4;++kk){
        const float* wrow = gsp_W2 + (size_t)(k+kk)*384 + t;
        float wS=wrow[0], wD=wrow[128], wT=wrow[256];
        #pragma unroll
        for(int r=0;r<8;++r){ float x=((const float*)&xv[r])[kk];
          accS[r]+=x*wS; accD[r]+=x*wD; accT[r]+=x*wT; }
      }
    }
    float* hsum = ws+WS_HSUM;
    #pragma unroll
    for(int r=0;r<8;++r){
      atomicAdd(&hsum[(size_t)ceI[rb+r]*LAT+t], accS[r]);
      od[rb+r][t]=accD[r]; ot[rb+r][t]=accT[r];
    }
  }
  __syncthreads();
  // md mlp
  { float b=md_b1[t];
    #pragma unroll
    for(int r=0;r<8;++r)acc[r]=b;
    mm_acc<8,LAT,LAT>(&od[rb][0], md_W1, LAT, t, acc);
    #pragma unroll
    for(int r=0;r<8;++r) hidB[rb+r][t]=silu_f(acc[r]); }
  __syncthreads();
  { int m=t&15, rr=rb+(t>>4); float a=md_b2[m];
    for (int k=0;k<LAT;++k) a += hidB[rr][k]*md_W2[(size_t)k*16+m];
    gdL[rr][m]=a; }
  __syncthreads();
  // mt mlp
  { float b=mt_b1[t];
    #pragma unroll
    for(int r=0;r<8;++r)acc[r]=b;
    mm_acc<8,LAT,LAT>(&ot[rb][0], mt_W1, LAT, t, acc);
    #pragma unroll
    for(int r=0;r<8;++r) hidB[rb+r][t]=silu_f(acc[r]); }
  __syncthreads();
  { int m=t&15, rr=rb+(t>>4); float a=mt_b2[m];
    for (int k=0;k<LAT;++k) a += hidB[rr][k]*mt_W2[(size_t)k*16+m];
    gtL[rr][m]=a; }
  __syncthreads();
  // dXij accumulation
  float* ndx = ws+WS_NDX;
  for (int idx=t; idx<144; idx+=128){
    int m=idx/9, d=idx-m*9;
    #pragma unroll
    for (int r=rb;r<rb+8;++r){
      float val = gdL[r][m]*sphL[r][d] + gtL[r][m]*xnb[r][idx];
      atomicAdd(&ndx[(size_t)ceI[r]*144+idx], val);
    }
  }
}

// ---- K6: node finalize: LN, residuals, so3_ln, Xp, nrm, gm mlp, outputs ----
__global__ __launch_bounds__(128) void k6_node(
  const float* __restrict__ h, const float* __restrict__ Xin,
  const float* __restrict__ ln_g,const float* __restrict__ ln_b,
  const float* __restrict__ Wvu,
  const float* __restrict__ gm_W1,const float* __restrict__ gm_b1,
  const float* __restrict__ gm_W2,const float* __restrict__ gm_b2,
  const float* __restrict__ ucp, const float* __restrict__ ws,
  float* __restrict__ outH, float* __restrict__ outX)
{
  __shared__ float cat[4][144], dxb[4][144], xnw[4][144], xp[4][144], hid[4][LAT];
  __shared__ float red[4][2][2], rinv[4][3], gX[4][16], wvu[256];
  const int t=threadIdx.x, n0=blockIdx.x*4;
  const float* hsum=ws+WS_HSUM; const float* ndx=ws+WS_NDX;
  const float uc=ucp[0], co=rsqrtf(uc*uc+1.f), ucco=uc*co;
  for (int idx=t; idx<256; idx+=128) wvu[idx]=Wvu[idx];
  for (int idx=t; idx<576; idx+=128){ int r=idx/144,c=idx%144; dxb[r][c]=ndx[(size_t)(n0+r)*144+c]; }
  float xv_[4];
  #pragma unroll
  for (int r=0;r<4;++r){
    float x=hsum[(size_t)(n0+r)*LAT+t]; xv_[r]=x;
    float s=x, ss=x*x;
    for (int off=32; off; off>>=1){ s+=__shfl_down(s,off,64); ss+=__shfl_down(ss,off,64); }
    if ((t&63)==0){ red[r][t>>6][0]=s; red[r][t>>6][1]=ss; }
  }
  __syncthreads();
  #pragma unroll
  for (int r=0;r<4;++r){
    float s=red[r][0][0]+red[r][1][0], ss=red[r][0][1]+red[r][1][1];
    float mu=s*(1.f/128.f), var=ss*(1.f/128.f)-mu*mu;
    float dh=(xv_[r]-mu)*rsqrtf(var+1e-5f)*ln_g[t]+ln_b[t];
    cat[r][t]=co*h[(size_t)(n0+r)*LAT+t]+ucco*dh;
  }
  if (t<12){
    int r=t/3, l=t-r*3;
    int s0 = (l==0)?0:((l==1)?1:4);
    int s1 = (l==0)?1:((l==1)?4:9);
    float sum=0.f;
    for (int m=0;m<16;++m)
      for (int d=s0;d<s1;++d){ float v=dxb[r][m*9+d]; sum+=v*v; }
    rinv[r][l]=rsqrtf(sum*(1.f/16.f)+1e-8f);
  }
  __syncthreads();
  for (int idx=t; idx<144; idx+=128){
    int d=idx%9; int l=(d==0)?0:((d<4)?1:2);
    #pragma unroll
    for (int r=0;r<4;++r)
      xnw[r][idx]=co*Xin[(size_t)(n0+r)*144+idx]+ucco*dxb[r][idx]*rinv[r][l];
  }
  __syncthreads();
  for (int idx=t; idx<144; idx+=128){
    int j=idx/9, i=idx-j*9;
    #pragma unroll
    for (int r=0;r<4;++r){
      float a=0.f;
      #pragma unroll
      for (int m=0;m<16;++m) a+=xnw[r][m*9+i]*wvu[m*16+j];
      xp[r][idx]=a;
    }
  }
  __syncthreads();
  if (t<64){ int r=t>>4, j=t&15; float s=1e-12f;
    #pragma unroll
    for (int i=0;i<9;++i){ float v=xp[r][j*9+i]; s+=v*v; }
    cat[r][128+j]=sqrtf(s); }
  __syncthreads();
  { float acc[4]; float b=gm_b1[t];
    #pragma unroll
    for(int r=0;r<4;++r)acc[r]=b;
    mm_acc<4,144,144>(&cat[0][0],gm_W1,LAT,t,acc);
    #pragma unroll
    for(int r=0;r<4;++r) hid[r][t]=silu_f(acc[r]); }
  __syncthreads();
  { float acc[4]; float b=gm_b2[t];
    #pragma unroll
    for(int r=0;r<4;++r)acc[r]=b;
    mm_acc<4,LAT,LAT>(&hid[0][0],gm_W2,144,t,acc);
    #pragma unroll
    for(int r=0;r<4;++r) outH[(size_t)(n0+r)*LAT+t]=cat[r][t]+acc[r]; }
  if (t<16){ float acc[4]; float b=gm_b2[128+t];
    #pragma unroll
    for(int r=0;r<4;++r)acc[r]=b;
    for (int k=0;k<LAT;++k){ float wk=gm_W2[(size_t)k*144+128+t];
      #pragma unroll
      for(int r=0;r<4;++r) acc[r]+=hid[r][k]*wk; }
    #pragma unroll
    for(int r=0;r<4;++r) gX[r][t]=acc[r]; }
  __syncthreads();
  for (int idx=t; idx<144; idx+=128){
    int j=idx/9;
    #pragma unroll
    for (int r=0;r<4;++r)
      outX[(size_t)(n0+r)*144+idx]=xnw[r][idx]+gX[r][j]*xp[r][idx];
  }
}

extern "C" void kernel_launch(void* const* d_in, const int* in_sizes, int n_in,
                              void* d_out, int out_size, void* d_ws, size_t ws_size,
                              hipStream_t stream)
{
  const float* h      = (const float*)d_in[0];
  const float* X      = (const float*)d_in[1];
  const float* t_ij   = (const float*)d_in[2];
  const float* sph    = (const float*)d_in[3];
  const float* ucp    = (const float*)d_in[4];
  const float* Wtq    = (const float*)d_in[5];
  const float* Wtk    = (const float*)d_in[6];
  const float* Wrs_W  = (const float*)d_in[7];
  const float* Wrs_b  = (const float*)d_in[8];
  const float* Wq_W   = (const float*)d_in[9];
  const float* Wq_b   = (const float*)d_in[10];
  const float* Wk_W   = (const float*)d_in[11];
  const float* Wk_b   = (const float*)d_in[12];
  const float* Wre_W  = (const float*)d_in[13];
  const float* ln_g   = (const float*)d_in[14];
  const float* ln_b   = (const float*)d_in[15];
  const float* Wvu    = (const float*)d_in[16];
  const float* gs_W1=(const float*)d_in[17], *gs_b1=(const float*)d_in[18],
             *gs_W2=(const float*)d_in[19], *gs_b2=(const float*)d_in[20];
  const float* gv_W1=(const float*)d_in[21], *gv_b1=(const float*)d_in[22],
             *gv_W2=(const float*)d_in[23], *gv_b2=(const float*)d_in[24];
  const float* gw_W1=(const float*)d_in[25], *gw_b1=(const float*)d_in[26],
             *gw_W2=(const float*)d_in[27], *gw_b2=(const float*)d_in[28];
  const float* gt_W1=(const float*)d_in[29], *gt_b1=(const float*)d_in[30],
             *gt_W2=(const float*)d_in[31], *gt_b2=(const float*)d_in[32];
  const float* gsp_W1=(const float*)d_in[33], *gsp_b1=(const float*)d_in[34],
             *gsp_W2=(const float*)d_in[35], *gsp_b2=(const float*)d_in[36];
  const float* md_W1=(const float*)d_in[37], *md_b1=(const float*)d_in[38],
             *md_W2=(const float*)d_in[39], *md_b2=(const float*)d_in[40];
  const float* mt_W1=(const float*)d_in[41], *mt_b1=(const float*)d_in[42],
             *mt_W2=(const float*)d_in[43], *mt_b2=(const float*)d_in[44];
  const float* gm_W1=(const float*)d_in[45], *gm_b1=(const float*)d_in[46],
             *gm_W2=(const float*)d_in[47], *gm_b2=(const float*)d_in[48];
  const int* ec = (const int*)d_in[49];
  const int* en = (const int*)d_in[50];
  (void)in_sizes; (void)n_in; (void)out_size; (void)ws_size;

  float* ws   = (float*)d_ws;
  float* outH = (float*)d_out;
  float* outX = outH + (size_t)N_NODES*LAT;
  float* outT = outX + (size_t)N_NODES*MUL*DD;

  k0_zero<<<dim3((unsigned)((ZERO_CNT+255)/256)), dim3(256), 0, stream>>>(ws + WS_ZERO);
  k1_node<<<dim3(N_NODES/16), dim3(128), 0, stream>>>(h, Wq_W,Wq_b, Wk_W,Wk_b,
      gv_W1,gv_b1,gv_W2,gv_b2, gs_W1,gs_b1,gs_W2,gs_b2, ws);
  k2_edge_w<<<dim3(E_EDGES/16), dim3(256), 0, stream>>>(X, sph, Wtq, Wtk, ec, en, ws);
  k3_edge_t<<<dim3(E_EDGES/16), dim3(256), 0, stream>>>(t_ij, ec, en,
      gw_W1,gw_b1,gw_W2,gw_b2, gt_W1,gt_b1,gt_W2,gt_b2,
      Wrs_W,Wrs_b, Wre_W, ucp, ws, outT);
  k4_softmax<<<dim3((E_EDGES*4)/256), dim3(256), 0, stream>>>(ec, ws);
  k5_edge_gate<<<dim3(E_EDGES/16), dim3(256), 0, stream>>>(X, sph, ec, en,
      gsp_W1,gsp_b1,gsp_W2,gsp_b2, md_W1,md_b1,md_W2,md_b2,
      mt_W1,mt_b1,mt_W2,mt_b2, ws);
  k6_node<<<dim3(N_NODES/4), dim3(128), 0, stream>>>(h, X, ln_g, ln_b, Wvu,
      gm_W1,gm_b1,gm_W2,gm_b2, ucp, ws, outH, outX);
}

// Round 2
// 810.073 us; speedup vs baseline: 2.6386x; 2.6386x over previous
//
#include <hip/hip_runtime.h>
#include <math.h>

#define N_NODES 20000
#define E_EDGES 160000
#define LAT 128
#define MUL 16
#define DD 9
#define TPD 48

// ---- workspace layout (float offsets) ----
#define WS_Q      ((size_t)0)
#define WS_K      (WS_Q + (size_t)N_NODES*LAT)
#define WS_V      (WS_K + (size_t)N_NODES*LAT)
#define WS_S      (WS_V + (size_t)N_NODES*LAT)
#define WS_W48    (WS_S + (size_t)N_NODES*LAT)
#define WS_SPATB  (WS_W48 + (size_t)E_EDGES*TPD)          // bf16 region: E*128 ushorts
#define WS_ALPHA  (WS_SPATB + (size_t)E_EDGES*LAT/2)
#define WS_ZERO   (WS_ALPHA + (size_t)E_EDGES*4)
#define WS_AMAX   WS_ZERO
#define WS_DEN    (WS_AMAX + (size_t)N_NODES*4)
#define WS_HSUM   (WS_DEN + (size_t)N_NODES*4)
#define WS_NDX    (WS_HSUM + (size_t)N_NODES*LAT)
#define WS_END    (WS_NDX + (size_t)N_NODES*MUL*DD)
#define ZERO_CNT  (WS_END - WS_ZERO)
#define WS_WB     WS_END                                   // ushort (bf16) packed weights

// packed weight offsets (ushort elements)
#define WOFF_WQ   0
#define WOFF_WK   16384
#define WOFF_GV1  32768
#define WOFF_GV2  49152
#define WOFF_GS1  65536
#define WOFF_GS2  81920
#define WOFF_GW1  98304
#define WOFF_GW2  106496
#define WOFF_GT1  122880
#define WOFF_GT2  139264
#define WOFF_WRS  155648
#define WOFF_WRE  172032
#define WOFF_GSP1 188416
#define WOFF_GSP2 204800
#define WOFF_MD1  253952
#define WOFF_MD2  270336
#define WOFF_MT1  272384
#define WOFF_MT2  288768
#define WB_TOTAL  290816

#define DEVI __device__ __forceinline__

typedef short short8 __attribute__((ext_vector_type(8)));
typedef float f32x4 __attribute__((ext_vector_type(4)));

DEVI float silu_f(float x){ return x / (1.f + expf(-x)); }
DEVI unsigned int fmap(float x){ unsigned int b=__float_as_uint(x); return (b&0x80000000u)? ~b : (b|0x80000000u); }
DEVI float funmap(unsigned int u){ return (u&0x80000000u)? __uint_as_float(u&0x7fffffffu) : __uint_as_float(~u); }
DEVI unsigned short f2b(float f){ unsigned int u=__float_as_uint(f); return (unsigned short)((u + 0x7fffu + ((u>>16)&1u))>>16); }
DEVI float b2f(unsigned short u){ return __uint_as_float(((unsigned int)u)<<16); }

DEVI f32x4 mfma16(short8 a, short8 b, f32x4 c){
  return __builtin_amdgcn_mfma_f32_16x16x32_bf16(a,b,c,0,0,0);
}

// acc[mt] (mt=0,1 → rows mt*16..mt*16+15) for column tile `ntile`
// act: bf16 LDS, row stride strideUS ushorts; Wp: packed bf16 weights
template<int KB>
DEVI void mm_tile2(const unsigned short* act, int strideUS, const unsigned short* Wp,
                   int ntile, int m, int quad, f32x4* acc){
  const unsigned short* wp = Wp + (size_t)ntile*KB*512 + (size_t)quad*128 + m*8;
  const unsigned short* a0 = act + m*strideUS + quad*8;
  const unsigned short* a1 = a0 + 16*strideUS;
  #pragma unroll
  for (int kb=0;kb<KB;++kb){
    short8 bfr = *(const short8*)(wp + (size_t)kb*512);
    short8 af0 = *(const short8*)(a0 + kb*32);
    short8 af1 = *(const short8*)(a1 + kb*32);
    acc[0]=mfma16(af0,bfr,acc[0]);
    acc[1]=mfma16(af1,bfr,acc[1]);
  }
}

// single m-tile, ntile 0 (for N=16 outputs)
template<int KB>
DEVI void mm_tile1(const unsigned short* act, int strideUS, const unsigned short* Wp,
                   int mtbase, int m, int quad, f32x4& acc){
  const unsigned short* wp = Wp + (size_t)quad*128 + m*8;
  const unsigned short* a0 = act + (mtbase*16+m)*strideUS + quad*8;
  #pragma unroll
  for (int kb=0;kb<KB;++kb){
    short8 bfr = *(const short8*)(wp + (size_t)kb*512);
    short8 af  = *(const short8*)(a0 + kb*32);
    acc=mfma16(af,bfr,acc);
  }
}

// f32 LDS-broadcast fallback matmul helper (k6)
template<int R, int KD, int LDSTRIDE>
DEVI void mm_acc(const float* src, const float* __restrict__ W, int wstride, int t, float* acc){
  #pragma unroll 2
  for (int k=0;k<KD;k+=4){
    float4 xv[R];
    #pragma unroll
    for (int r=0;r<R;++r) xv[r] = *(const float4*)(src + r*LDSTRIDE + k);
    #pragma unroll
    for (int kk=0;kk<4;++kk){
      float wk = W[(size_t)(k+kk)*wstride + t];
      #pragma unroll
      for (int r=0;r<R;++r) acc[r] += ((const float*)&xv[r])[kk]*wk;
    }
  }
}

// ---- K0: zero accumulator region ----
__global__ void k0_zero(float* __restrict__ z){
  size_t i = (size_t)blockIdx.x*256 + threadIdx.x;
  if (i < ZERO_CNT) z[i] = 0.f;
}

// ---- Kpack: convert all weights f32 -> packed bf16 fragment order ----
// dst idx = (((n_tile*KB + k_block)*4 + quad)*16 + n_in)*8 + j ; k=k_block*32+quad*8+j
__global__ __launch_bounds__(256) void k_pack(
  const float* __restrict__ Wq,const float* __restrict__ Wk,
  const float* __restrict__ gv1,const float* __restrict__ gv2,
  const float* __restrict__ gs1,const float* __restrict__ gs2,
  const float* __restrict__ gw1,const float* __restrict__ gw2,
  const float* __restrict__ gt1,const float* __restrict__ gt2,
  const float* __restrict__ Wrs,const float* __restrict__ Wre,
  const float* __restrict__ gsp1,const float* __restrict__ gsp2,
  const float* __restrict__ md1,const float* __restrict__ md2,
  const float* __restrict__ mt1,const float* __restrict__ mt2,
  unsigned short* __restrict__ dst)
{
  int i = blockIdx.x*256 + threadIdx.x;
  if (i >= WB_TOTAL) return;
  const int off[19] = {0,16384,32768,49152,65536,81920,98304,106496,122880,139264,
                       155648,172032,188416,204800,253952,270336,272384,288768,290816};
  int mi=0;
  while (i >= off[mi+1]) ++mi;
  int li = i - off[mi];
  int N = (mi==13)?384:((mi==15||mi==17)?16:128);
  int Ksrc = (mi==6)?48:128;
  int KB = (mi==6)?2:4;
  int j = li&7; int t = li>>3;
  int n_in = t&15; t>>=4;
  int quad = t&3; t>>=2;
  int k_block = t % KB; int n_tile = t / KB;
  int k = k_block*32 + quad*8 + j;
  int n = n_tile*16 + n_in;
  const float* src;
  switch(mi){
    case 0: src=Wq; break;  case 1: src=Wk; break;
    case 2: src=gv1; break; case 3: src=gv2; break;
    case 4: src=gs1; break; case 5: src=gs2; break;
    case 6: src=gw1; break; case 7: src=gw2; break;
    case 8: src=gt1; break; case 9: src=gt2; break;
    case 10: src=Wrs; break; case 11: src=Wre; break;
    case 12: src=gsp1; break; case 13: src=gsp2; break;
    case 14: src=md1; break; case 15: src=md2; break;
    default: src=(mi==16)?mt1:mt2; break;
  }
  float v = (k < Ksrc) ? src[(size_t)k*N + n] : 0.f;
  dst[i] = f2b(v);
}

// ---- K1: per-node Q,K,V(gv),S(gs) via MFMA, 32 nodes/block ----
__global__ __launch_bounds__(256) void k1_node(const float* __restrict__ h,
  const unsigned short* __restrict__ WB,
  const float* __restrict__ Wq_b,const float* __restrict__ Wk_b,
  const float* __restrict__ gv_b1,const float* __restrict__ gv_b2,
  const float* __restrict__ gs_b1,const float* __restrict__ gs_b2,
  float* __restrict__ ws)
{
  __shared__ __align__(16) unsigned short B0[32*136], B1[32*136];
  const int tid=threadIdx.x, lane=tid&63, w=tid>>6, m=lane&15, quad=lane>>4;
  const int n0=blockIdx.x*32;
  for (int idx=tid; idx<4096; idx+=256){ int r=idx>>7,c=idx&127;
    B0[r*136+c]=f2b(h[(size_t)(n0+r)*128+c]); }
  __syncthreads();
  f32x4 z4 = {0.f,0.f,0.f,0.f};
  // Q
  { f32x4 acc[2][2]={{z4,z4},{z4,z4}};
    #pragma unroll
    for(int i=0;i<2;++i) mm_tile2<4>(B0,136,WB+WOFF_WQ, w*2+i, m, quad, acc[i]);
    #pragma unroll
    for(int i=0;i<2;++i){ int col=(w*2+i)*16+m; float bv=Wq_b[col];
      #pragma unroll
      for(int mt=0;mt<2;++mt)
        #pragma unroll
        for(int r=0;r<4;++r){ int row=mt*16+quad*4+r;
          ws[WS_Q+(size_t)(n0+row)*128+col]=acc[i][mt][r]+bv; } } }
  // K
  { f32x4 acc[2][2]={{z4,z4},{z4,z4}};
    #pragma unroll
    for(int i=0;i<2;++i) mm_tile2<4>(B0,136,WB+WOFF_WK, w*2+i, m, quad, acc[i]);
    #pragma unroll
    for(int i=0;i<2;++i){ int col=(w*2+i)*16+m; float bv=Wk_b[col];
      #pragma unroll
      for(int mt=0;mt<2;++mt)
        #pragma unroll
        for(int r=0;r<4;++r){ int row=mt*16+quad*4+r;
          ws[WS_K+(size_t)(n0+row)*128+col]=acc[i][mt][r]+bv; } } }
  // gv hidden
  { f32x4 acc[2][2]={{z4,z4},{z4,z4}};
    #pragma unroll
    for(int i=0;i<2;++i) mm_tile2<4>(B0,136,WB+WOFF_GV1, w*2+i, m, quad, acc[i]);
    #pragma unroll
    for(int i=0;i<2;++i){ int col=(w*2+i)*16+m; float bv=gv_b1[col];
      #pragma unroll
      for(int mt=0;mt<2;++mt)
        #pragma unroll
        for(int r=0;r<4;++r) B1[(mt*16+quad*4+r)*136+col]=f2b(silu_f(acc[i][mt][r]+bv)); } }
  __syncthreads();
  // V out
  { f32x4 acc[2][2]={{z4,z4},{z4,z4}};
    #pragma unroll
    for(int i=0;i<2;++i) mm_tile2<4>(B1,136,WB+WOFF_GV2, w*2+i, m, quad, acc[i]);
    #pragma unroll
    for(int i=0;i<2;++i){ int col=(w*2+i)*16+m; float bv=gv_b2[col];
      #pragma unroll
      for(int mt=0;mt<2;++mt)
        #pragma unroll
        for(int r=0;r<4;++r){ int row=mt*16+quad*4+r;
          ws[WS_V+(size_t)(n0+row)*128+col]=acc[i][mt][r]+bv; } } }
  __syncthreads();
  // gs hidden
  { f32x4 acc[2][2]={{z4,z4},{z4,z4}};
    #pragma unroll
    for(int i=0;i<2;++i) mm_tile2<4>(B0,136,WB+WOFF_GS1, w*2+i, m, quad, acc[i]);
    #pragma unroll
    for(int i=0;i<2;++i){ int col=(w*2+i)*16+m; float bv=gs_b1[col];
      #pragma unroll
      for(int mt=0;mt<2;++mt)
        #pragma unroll
        for(int r=0;r<4;++r) B1[(mt*16+quad*4+r)*136+col]=f2b(silu_f(acc[i][mt][r]+bv)); } }
  __syncthreads();
  // S out
  { f32x4 acc[2][2]={{z4,z4},{z4,z4}};
    #pragma unroll
    for(int i=0;i<2;++i) mm_tile2<4>(B1,136,WB+WOFF_GS2, w*2+i, m, quad, acc[i]);
    #pragma unroll
    for(int i=0;i<2;++i){ int col=(w*2+i)*16+m; float bv=gs_b2[col];
      #pragma unroll
      for(int mt=0;mt<2;++mt)
        #pragma unroll
        for(int r=0;r<4;++r){ int row=mt*16+quad*4+r;
          ws[WS_S+(size_t)(n0+row)*128+col]=acc[i][mt][r]+bv; } } }
}

// ---- K2: per-edge w (eq_linear + rejection + slice dots) — f32, unchanged ----
__global__ __launch_bounds__(256) void k2_edge_w(
  const float* __restrict__ Xin, const float* __restrict__ sph,
  const float* __restrict__ Wtq, const float* __restrict__ Wtk,
  const int* __restrict__ ec, const int* __restrict__ en, float* __restrict__ ws)
{
  __shared__ float xc[16][144], xn[16][144], sphL[16][9];
  __shared__ float wq[768], wkk[768];
  __shared__ int ceI[16], nbI[16];
  const int tid=threadIdx.x, e0=blockIdx.x*16;
  if (tid<16){ ceI[tid]=ec[e0+tid]; nbI[tid]=en[e0+tid]; }
  for (int idx=tid; idx<768; idx+=256){ wq[idx]=Wtq[idx]; wkk[idx]=Wtk[idx]; }
  __syncthreads();
  for (int idx=tid; idx<2304; idx+=256){ int r=idx/144,c=idx%144;
    xc[r][c]=Xin[(size_t)ceI[r]*144+c]; xn[r][c]=Xin[(size_t)nbI[r]*144+c]; }
  if (tid<144){ int r=tid/9,c=tid%9; sphL[r][c]=sph[(size_t)(e0+r)*9+c]; }
  __syncthreads();
  const int el=tid>>4, j=tid&15;
  float xq[9], xk[9];
  const int ss[3]={0,1,4}, se[3]={1,4,9};
  #pragma unroll
  for (int l=0;l<3;++l){
    for (int mm2=ss[l]; mm2<se[l]; ++mm2){
      float aq=0.f, ak=0.f;
      #pragma unroll
      for (int i=0;i<16;++i){
        float wql = wq[l*256 + j*16 + i], wkl = wkk[l*256 + j*16 + i];
        aq += wql*xc[el][i*9+mm2];
        ak += wkl*xn[el][i*9+mm2];
      }
      xq[mm2]=aq; xk[mm2]=ak;
    }
  }
  float dq=0.f, dk=0.f;
  #pragma unroll
  for (int d=0; d<9; ++d){ dq += xq[d]*sphL[el][d]; dk += xk[d]*sphL[el][d]; }
  #pragma unroll
  for (int d=0; d<9; ++d){ xq[d] -= dq*sphL[el][d]; xk[d] -= dk*sphL[el][d]; }
  const float isc[3] = {1.f, 0.5773502691896258f, 0.4472135954999579f};
  #pragma unroll
  for (int l=0;l<3;++l){
    float s=0.f;
    for (int mm2=ss[l]; mm2<se[l]; ++mm2) s += xq[mm2]*xk[mm2];
    ws[WS_W48 + (size_t)(e0+el)*TPD + l*16 + j] = s*isc[l];
  }
}

// ---- K3: per-edge t-update + spatial + alpha via MFMA, 32 edges/block ----
__global__ __launch_bounds__(256) void k3_edge_t(
  const float* __restrict__ t_in, const int* __restrict__ ec, const int* __restrict__ en,
  const unsigned short* __restrict__ WB,
  const float* __restrict__ gw_b1,const float* __restrict__ gw_b2,
  const float* __restrict__ gt_b1,const float* __restrict__ gt_b2,
  const float* __restrict__ Wrs_b,
  const float* __restrict__ ucp, float* __restrict__ ws, float* __restrict__ outT)
{
  __shared__ __align__(16) unsigned short tin_b[32*136], hid_b[32*136], tnw_b[32*136], wb_b[32*72];
  __shared__ float qk[32*132];
  __shared__ int ceI[32], nbI[32];
  const int tid=threadIdx.x, lane=tid&63, w=tid>>6, m=lane&15, quad=lane>>4;
  const int e0=blockIdx.x*32;
  if (tid<32){ ceI[tid]=ec[e0+tid]; nbI[tid]=en[e0+tid]; }
  __syncthreads();
  const float* Qp=ws+WS_Q; const float* Kp=ws+WS_K;
  for (int idx=tid; idx<4096; idx+=256){
    int r=idx>>7, c=idx&127;
    tin_b[r*136+c] = f2b(t_in[(size_t)(e0+r)*128+c]);
    qk[r*132+c] = Qp[(size_t)ceI[r]*128+c]*Kp[(size_t)nbI[r]*128+c];
  }
  for (int idx=tid; idx<2048; idx+=256){
    int r=idx>>6, c=idx&63;
    wb_b[r*72+c] = (c<48)? f2b(ws[WS_W48+(size_t)(e0+r)*TPD+c]) : (unsigned short)0;
  }
  __syncthreads();
  const float uc=ucp[0], co=rsqrtf(uc*uc+1.f), ucco=uc*co;
  f32x4 z4 = {0.f,0.f,0.f,0.f};
  // P1: gw hidden (K=48 padded to 64)
  { f32x4 acc[2][2]={{z4,z4},{z4,z4}};
    #pragma unroll
    for(int i=0;i<2;++i) mm_tile2<2>(wb_b,72,WB+WOFF_GW1, w*2+i, m, quad, acc[i]);
    #pragma unroll
    for(int i=0;i<2;++i){ int col=(w*2+i)*16+m; float bv=gw_b1[col];
      #pragma unroll
      for(int mt=0;mt<2;++mt)
        #pragma unroll
        for(int r=0;r<4;++r) hid_b[(mt*16+quad*4+r)*136+col]=f2b(silu_f(acc[i][mt][r]+bv)); } }
  __syncthreads();
  // P2: gw out -> accw (regs)
  f32x4 accw[2][2]={{z4,z4},{z4,z4}};
  #pragma unroll
  for(int i=0;i<2;++i) mm_tile2<4>(hid_b,136,WB+WOFF_GW2, w*2+i, m, quad, accw[i]);
  __syncthreads();
  // P3: gt hidden
  { f32x4 acc[2][2]={{z4,z4},{z4,z4}};
    #pragma unroll
    for(int i=0;i<2;++i) mm_tile2<4>(tin_b,136,WB+WOFF_GT1, w*2+i, m, quad, acc[i]);
    #pragma unroll
    for(int i=0;i<2;++i){ int col=(w*2+i)*16+m; float bv=gt_b1[col];
      #pragma unroll
      for(int mt=0;mt<2;++mt)
        #pragma unroll
        for(int r=0;r<4;++r) hid_b[(mt*16+quad*4+r)*136+col]=f2b(silu_f(acc[i][mt][r]+bv)); } }
  __syncthreads();
  // P4: gt out; dt = gw*gt; residual -> t_new
  { f32x4 acct[2][2]={{z4,z4},{z4,z4}};
    #pragma unroll
    for(int i=0;i<2;++i) mm_tile2<4>(hid_b,136,WB+WOFF_GT2, w*2+i, m, quad, acct[i]);
    #pragma unroll
    for(int i=0;i<2;++i){ int col=(w*2+i)*16+m; float bw=gw_b2[col], bt=gt_b2[col];
      #pragma unroll
      for(int mt=0;mt<2;++mt)
        #pragma unroll
        for(int r=0;r<4;++r){ int row=mt*16+quad*4+r;
          float dt=(accw[i][mt][r]+bw)*(acct[i][mt][r]+bt);
          float tn=co*b2f(tin_b[row*136+col]) + ucco*dt;
          tnw_b[row*136+col]=f2b(tn);
          outT[(size_t)(e0+row)*128+col]=tn; } } }
  __syncthreads();
  unsigned short* spatB = (unsigned short*)(ws+WS_SPATB);
  // P5: spatial = (t_new@Wrs + b) * S[nb]  (store bf16)
  { f32x4 acc[2][2]={{z4,z4},{z4,z4}};
    #pragma unroll
    for(int i=0;i<2;++i) mm_tile2<4>(tnw_b,136,WB+WOFF_WRS, w*2+i, m, quad, acc[i]);
    #pragma unroll
    for(int i=0;i<2;++i){ int col=(w*2+i)*16+m; float bv=Wrs_b[col];
      #pragma unroll
      for(int mt=0;mt<2;++mt)
        #pragma unroll
        for(int r=0;r<4;++r){ int row=mt*16+quad*4+r;
          float sv=ws[WS_S+(size_t)nbI[row]*128+col];
          spatB[(size_t)(e0+row)*128+col]=f2b((acc[i][mt][r]+bv)*sv); } } }
  // P6: re = silu(t_new@Wre); alpha + segment max (wave w == head w)
  { f32x4 acc[2][2]={{z4,z4},{z4,z4}};
    #pragma unroll
    for(int i=0;i<2;++i) mm_tile2<4>(tnw_b,136,WB+WOFF_WRE, w*2+i, m, quad, acc[i]);
    unsigned int* amaxu=(unsigned int*)(ws+WS_AMAX);
    #pragma unroll
    for(int mt=0;mt<2;++mt)
      #pragma unroll
      for(int r=0;r<4;++r){ int row=mt*16+quad*4+r;
        float p=0.f;
        #pragma unroll
        for(int i=0;i<2;++i){ int col=(w*2+i)*16+m;
          p += qk[row*132+col]*silu_f(acc[i][mt][r]); }
        p += __shfl_xor(p,1); p += __shfl_xor(p,2); p += __shfl_xor(p,4); p += __shfl_xor(p,8);
        if (m==0){
          float aval = p * 0.17677669529663687f; // 1/sqrt(32)
          int e=e0+row;
          ws[WS_ALPHA+(size_t)e*4+w]=aval;
          atomicMax(&amaxu[(size_t)ceI[row]*4+w], fmap(aval));
        } } }
}

// ---- K4: ex = exp(alpha - amax[center]); den += ex ----
__global__ __launch_bounds__(256) void k4_softmax(const int* __restrict__ ec, float* __restrict__ ws){
  int i = blockIdx.x*256 + threadIdx.x;
  if (i >= E_EDGES*4) return;
  int e = i>>2, hh = i&3;
  int c = ec[e];
  float a = ws[WS_ALPHA + i];
  const unsigned int* amaxu = (const unsigned int*)(ws + WS_AMAX);
  float am = funmap(amaxu[(size_t)c*4+hh]);
  float exv = expf(a - am);
  ws[WS_ALPHA + i] = exv;
  atomicAdd(&ws[WS_DEN + (size_t)c*4 + hh], exv);
}

// ---- K5: per-edge gates + segment sums via MFMA, 32 edges/block ----
__global__ __launch_bounds__(256) void k5_edge_gate(
  const float* __restrict__ Xin, const float* __restrict__ sph,
  const int* __restrict__ ec, const int* __restrict__ en,
  const unsigned short* __restrict__ WB,
  const float* __restrict__ gsp_b1,const float* __restrict__ gsp_b2,
  const float* __restrict__ md_b1,const float* __restrict__ md_b2,
  const float* __restrict__ mt_b1,const float* __restrict__ mt_b2,
  float* __restrict__ ws)
{
  __shared__ __align__(16) unsigned short B0[32*136], B1[32*136], B2[32*136], B3[32*136];
  __shared__ float gdL[32*16], gtL[32*16], attnL[32*4];
  __shared__ int ceI[32], nbI[32];
  const int tid=threadIdx.x, lane=tid&63, w=tid>>6, m=lane&15, quad=lane>>4;
  const int e0=blockIdx.x*32;
  if (tid<32){ ceI[tid]=ec[e0+tid]; nbI[tid]=en[e0+tid]; }
  __syncthreads();
  if (tid<128){ int r=tid>>2, hh=tid&3;
    attnL[tid] = ws[WS_ALPHA+(size_t)(e0+r)*4+hh] / ws[WS_DEN+(size_t)ceI[r]*4+hh]; }
  __syncthreads();
  const float* Vp=ws+WS_V;
  const unsigned short* spatB=(const unsigned short*)(ws+WS_SPATB);
  for (int idx=tid; idx<4096; idx+=256){ int r=idx>>7,c=idx&127;
    float v = attnL[r*4+(c>>5)]*Vp[(size_t)nbI[r]*128+c] + b2f(spatB[(size_t)(e0+r)*128+c]);
    B0[r*136+c]=f2b(v); }
  __syncthreads();
  f32x4 z4 = {0.f,0.f,0.f,0.f};
  // P1: gsp hidden B0 -> B1
  { f32x4 acc[2][2]={{z4,z4},{z4,z4}};
    #pragma unroll
    for(int i=0;i<2;++i) mm_tile2<4>(B0,136,WB+WOFF_GSP1, w*2+i, m, quad, acc[i]);
    #pragma unroll
    for(int i=0;i<2;++i){ int col=(w*2+i)*16+m; float bv=gsp_b1[col];
      #pragma unroll
      for(int mt=0;mt<2;++mt)
        #pragma unroll
        for(int r=0;r<4;++r) B1[(mt*16+quad*4+r)*136+col]=f2b(silu_f(acc[i][mt][r]+bv)); } }
  __syncthreads();
  // P2: gsp out (384 cols): o_s atomics; o_d -> B2; o_t -> B3
  { f32x4 acc[3][2][2];
    #pragma unroll
    for(int g2=0;g2<3;++g2)
      #pragma unroll
      for(int i=0;i<2;++i){ acc[g2][i][0]=z4; acc[g2][i][1]=z4; }
    #pragma unroll
    for(int g2=0;g2<3;++g2)
      #pragma unroll
      for(int i=0;i<2;++i)
        mm_tile2<4>(B1,136,WB+WOFF_GSP2, g2*8+w*2+i, m, quad, acc[g2][i]);
    float* hsum=ws+WS_HSUM;
    #pragma unroll
    for(int i=0;i<2;++i){ int col=(w*2+i)*16+m;
      float bS=gsp_b2[col], bD=gsp_b2[128+col], bT=gsp_b2[256+col];
      #pragma unroll
      for(int mt=0;mt<2;++mt)
        #pragma unroll
        for(int r=0;r<4;++r){ int row=mt*16+quad*4+r;
          atomicAdd(&hsum[(size_t)ceI[row]*128+col], acc[0][i][mt][r]+bS);
          B2[row*136+col]=f2b(acc[1][i][mt][r]+bD);
          B3[row*136+col]=f2b(acc[2][i][mt][r]+bT); } } }
  __syncthreads();
  // P3: md hidden B2 -> B0
  { f32x4 acc[2][2]={{z4,z4},{z4,z4}};
    #pragma unroll
    for(int i=0;i<2;++i) mm_tile2<4>(B2,136,WB+WOFF_MD1, w*2+i, m, quad, acc[i]);
    #pragma unroll
    for(int i=0;i<2;++i){ int col=(w*2+i)*16+m; float bv=md_b1[col];
      #pragma unroll
      for(int mt=0;mt<2;++mt)
        #pragma unroll
        for(int r=0;r<4;++r) B0[(mt*16+quad*4+r)*136+col]=f2b(silu_f(acc[i][mt][r]+bv)); } }
  __syncthreads();
  // P4: mt hidden B3 -> B2
  { f32x4 acc[2][2]={{z4,z4},{z4,z4}};
    #pragma unroll
    for(int i=0;i<2;++i) mm_tile2<4>(B3,136,WB+WOFF_MT1, w*2+i, m, quad, acc[i]);
    #pragma unroll
    for(int i=0;i<2;++i){ int col=(w*2+i)*16+m; float bv=mt_b1[col];
      #pragma unroll
      for(int mt=0;mt<2;++mt)
        #pragma unroll
        for(int r=0;r<4;++r) B2[(mt*16+quad*4+r)*136+col]=f2b(silu_f(acc[i][mt][r]+bv)); } }
  __syncthreads();
  // P5: gd (waves 0-1 from B0), gtt (waves 2-3 from B2), N=16
  { if (w<2){
      f32x4 a=z4; mm_tile1<4>(B0,136,WB+WOFF_MD2, w, m, quad, a);
      #pragma unroll
      for(int r=0;r<4;++r) gdL[(w*16+quad*4+r)*16+m]=a[r]+md_b2[m];
    } else {
      f32x4 a=z4; mm_tile1<4>(B2,136,WB+WOFF_MT2, w-2, m, quad, a);
      #pragma unroll
      for(int r=0;r<4;++r) gtL[((w-2)*16+quad*4+r)*16+m]=a[r]+mt_b2[m];
    } }
  __syncthreads();
  // P6: dXij atomics
  float* ndx=ws+WS_NDX;
  for (int idx=tid; idx<4608; idx+=256){
    int r=idx/144, c=idx-r*144; int mm2=c/9, d=c-mm2*9;
    float val = gdL[r*16+mm2]*sph[(size_t)(e0+r)*9+d] + gtL[r*16+mm2]*Xin[(size_t)nbI[r]*144+c];
    atomicAdd(&ndx[(size_t)ceI[r]*144+c], val);
  }
}

// ---- K6: node finalize (unchanged f32) ----
__global__ __launch_bounds__(128) void k6_node(
  const float* __restrict__ h, const float* __restrict__ Xin,
  const float* __restrict__ ln_g,const float* __restrict__ ln_b,
  const float* __restrict__ Wvu,
  const float* __restrict__ gm_W1,const float* __restrict__ gm_b1,
  const float* __restrict__ gm_W2,const float* __restrict__ gm_b2,
  const float* __restrict__ ucp, const float* __restrict__ ws,
  float* __restrict__ outH, float* __restrict__ outX)
{
  __shared__ float cat[4][144], dxb[4][144], xnw[4][144], xp[4][144], hid[4][LAT];
  __shared__ float red[4][2][2], rinv[4][3], gX[4][16], wvu[256];
  const int t=threadIdx.x, n0=blockIdx.x*4;
  const float* hsum=ws+WS_HSUM; const float* ndx=ws+WS_NDX;
  const float uc=ucp[0], co=rsqrtf(uc*uc+1.f), ucco=uc*co;
  for (int idx=t; idx<256; idx+=128) wvu[idx]=Wvu[idx];
  for (int idx=t; idx<576; idx+=128){ int r=idx/144,c=idx%144; dxb[r][c]=ndx[(size_t)(n0+r)*144+c]; }
  float xv_[4];
  #pragma unroll
  for (int r=0;r<4;++r){
    float x=hsum[(size_t)(n0+r)*LAT+t]; xv_[r]=x;
    float s=x, ss=x*x;
    for (int off=32; off; off>>=1){ s+=__shfl_down(s,off,64); ss+=__shfl_down(ss,off,64); }
    if ((t&63)==0){ red[r][t>>6][0]=s; red[r][t>>6][1]=ss; }
  }
  __syncthreads();
  #pragma unroll
  for (int r=0;r<4;++r){
    float s=red[r][0][0]+red[r][1][0], ss=red[r][0][1]+red[r][1][1];
    float mu=s*(1.f/128.f), var=ss*(1.f/128.f)-mu*mu;
    float dh=(xv_[r]-mu)*rsqrtf(var+1e-5f)*ln_g[t]+ln_b[t];
    cat[r][t]=co*h[(size_t)(n0+r)*LAT+t]+ucco*dh;
  }
  if (t<12){
    int r=t/3, l=t-r*3;
    int s0 = (l==0)?0:((l==1)?1:4);
    int s1 = (l==0)?1:((l==1)?4:9);
    float sum=0.f;
    for (int mm2=0;mm2<16;++mm2)
      for (int d=s0;d<s1;++d){ float v=dxb[r][mm2*9+d]; sum+=v*v; }
    rinv[r][l]=rsqrtf(sum*(1.f/16.f)+1e-8f);
  }
  __syncthreads();
  for (int idx=t; idx<144; idx+=128){
    int d=idx%9; int l=(d==0)?0:((d<4)?1:2);
    #pragma unroll
    for (int r=0;r<4;++r)
      xnw[r][idx]=co*Xin[(size_t)(n0+r)*144+idx]+ucco*dxb[r][idx]*rinv[r][l];
  }
  __syncthreads();
  for (int idx=t; idx<144; idx+=128){
    int j=idx/9, i=idx-j*9;
    #pragma unroll
    for (int r=0;r<4;++r){
      float a=0.f;
      #pragma unroll
      for (int mm2=0;mm2<16;++mm2) a+=xnw[r][mm2*9+i]*wvu[mm2*16+j];
      xp[r][idx]=a;
    }
  }
  __syncthreads();
  if (t<64){ int r=t>>4, j=t&15; float s=1e-12f;
    #pragma unroll
    for (int i=0;i<9;++i){ float v=xp[r][j*9+i]; s+=v*v; }
    cat[r][128+j]=sqrtf(s); }
  __syncthreads();
  { float acc[4]; float b=gm_b1[t];
    #pragma unroll
    for(int r=0;r<4;++r)acc[r]=b;
    mm_acc<4,144,144>(&cat[0][0],gm_W1,LAT,t,acc);
    #pragma unroll
    for(int r=0;r<4;++r) hid[r][t]=silu_f(acc[r]); }
  __syncthreads();
  { float acc[4]; float b=gm_b2[t];
    #pragma unroll
    for(int r=0;r<4;++r)acc[r]=b;
    mm_acc<4,LAT,LAT>(&hid[0][0],gm_W2,144,t,acc);
    #pragma unroll
    for(int r=0;r<4;++r) outH[(size_t)(n0+r)*LAT+t]=cat[r][t]+acc[r]; }
  if (t<16){ float acc[4]; float b=gm_b2[128+t];
    #pragma unroll
    for(int r=0;r<4;++r)acc[r]=b;
    for (int k=0;k<LAT;++k){ float wk=gm_W2[(size_t)k*144+128+t];
      #pragma unroll
      for(int r=0;r<4;++r) acc[r]+=hid[r][k]*wk; }
    #pragma unroll
    for(int r=0;r<4;++r) gX[r][t]=acc[r]; }
  __syncthreads();
  for (int idx=t; idx<144; idx+=128){
    int j=idx/9;
    #pragma unroll
    for (int r=0;r<4;++r)
      outX[(size_t)(n0+r)*144+idx]=xnw[r][idx]+gX[r][j]*xp[r][idx];
  }
}

extern "C" void kernel_launch(void* const* d_in, const int* in_sizes, int n_in,
                              void* d_out, int out_size, void* d_ws, size_t ws_size,
                              hipStream_t stream)
{
  const float* h      = (const float*)d_in[0];
  const float* X      = (const float*)d_in[1];
  const float* t_ij   = (const float*)d_in[2];
  const float* sph    = (const float*)d_in[3];
  const float* ucp    = (const float*)d_in[4];
  const float* Wtq    = (const float*)d_in[5];
  const float* Wtk    = (const float*)d_in[6];
  const float* Wrs_W  = (const float*)d_in[7];
  const float* Wrs_b  = (const float*)d_in[8];
  const float* Wq_W   = (const float*)d_in[9];
  const float* Wq_b   = (const float*)d_in[10];
  const float* Wk_W   = (const float*)d_in[11];
  const float* Wk_b   = (const float*)d_in[12];
  const float* Wre_W  = (const float*)d_in[13];
  const float* ln_g   = (const float*)d_in[14];
  const float* ln_b   = (const float*)d_in[15];
  const float* Wvu    = (const float*)d_in[16];
  const float* gs_W1=(const float*)d_in[17], *gs_b1=(const float*)d_in[18],
             *gs_W2=(const float*)d_in[19], *gs_b2=(const float*)d_in[20];
  const float* gv_W1=(const float*)d_in[21], *gv_b1=(const float*)d_in[22],
             *gv_W2=(const float*)d_in[23], *gv_b2=(const float*)d_in[24];
  const float* gw_W1=(const float*)d_in[25], *gw_b1=(const float*)d_in[26],
             *gw_W2=(const float*)d_in[27], *gw_b2=(const float*)d_in[28];
  const float* gt_W1=(const float*)d_in[29], *gt_b1=(const float*)d_in[30],
             *gt_W2=(const float*)d_in[31], *gt_b2=(const float*)d_in[32];
  const float* gsp_W1=(const float*)d_in[33], *gsp_b1=(const float*)d_in[34],
             *gsp_W2=(const float*)d_in[35], *gsp_b2=(const float*)d_in[36];
  const float* md_W1=(const float*)d_in[37], *md_b1=(const float*)d_in[38],
             *md_W2=(const float*)d_in[39], *md_b2=(const float*)d_in[40];
  const float* mt_W1=(const float*)d_in[41], *mt_b1=(const float*)d_in[42],
             *mt_W2=(const float*)d_in[43], *mt_b2=(const float*)d_in[44];
  const float* gm_W1=(const float*)d_in[45], *gm_b1=(const float*)d_in[46],
             *gm_W2=(const float*)d_in[47], *gm_b2=(const float*)d_in[48];
  const int* ec = (const int*)d_in[49];
  const int* en = (const int*)d_in[50];
  (void)in_sizes; (void)n_in; (void)out_size; (void)ws_size;

  float* ws   = (float*)d_ws;
  unsigned short* WB = (unsigned short*)(ws + WS_WB);
  float* outH = (float*)d_out;
  float* outX = outH + (size_t)N_NODES*LAT;
  float* outT = outX + (size_t)N_NODES*MUL*DD;

  k0_zero<<<dim3((unsigned)((ZERO_CNT+255)/256)), dim3(256), 0, stream>>>(ws + WS_ZERO);
  k_pack<<<dim3((WB_TOTAL+255)/256), dim3(256), 0, stream>>>(
      Wq_W,Wk_W, gv_W1,gv_W2, gs_W1,gs_W2, gw_W1,gw_W2, gt_W1,gt_W2,
      Wrs_W,Wre_W, gsp_W1,gsp_W2, md_W1,md_W2, mt_W1,mt_W2, WB);
  k1_node<<<dim3(N_NODES/32), dim3(256), 0, stream>>>(h, WB, Wq_b, Wk_b,
      gv_b1,gv_b2, gs_b1,gs_b2, ws);
  k2_edge_w<<<dim3(E_EDGES/16), dim3(256), 0, stream>>>(X, sph, Wtq, Wtk, ec, en, ws);
  k3_edge_t<<<dim3(E_EDGES/32), dim3(256), 0, stream>>>(t_ij, ec, en, WB,
      gw_b1,gw_b2, gt_b1,gt_b2, Wrs_b, ucp, ws, outT);
  k4_softmax<<<dim3((E_EDGES*4)/256), dim3(256), 0, stream>>>(ec, ws);
  k5_edge_gate<<<dim3(E_EDGES/32), dim3(256), 0, stream>>>(X, sph, ec, en, WB,
      gsp_b1,gsp_b2, md_b1,md_b2, mt_b1,mt_b2, ws);
  k6_node<<<dim3(N_NODES/4), dim3(128), 0, stream>>>(h, X, ln_g, ln_b, Wvu,
      gm_W1,gm_b1,gm_W2,gm_b2, ucp, ws, outH, outX);
}